// Round 1
// baseline (656.188 us; speedup 1.0000x reference)
//
#include <hip/hip_runtime.h>

typedef __bf16 bf16x8 __attribute__((ext_vector_type(8)));
typedef float  f32x4  __attribute__((ext_vector_type(4)));
typedef unsigned short us8 __attribute__((ext_vector_type(8)));

// ---------------- weight prep: f32 W[k][n] -> transposed bf16 hi/lo WT[n][k] ----------------
__global__ void prep_w(const float* __restrict__ W, unsigned short* __restrict__ hiT,
                       unsigned short* __restrict__ loT) {
    int i = blockIdx.x * 256 + threadIdx.x;   // 0..16383
    int k = i >> 7;        // input-dim row of W
    int n = i & 127;       // output-dim col of W
    float f = W[i];
    __bf16 h = (__bf16)f;
    __bf16 l = (__bf16)(f - (float)h);
    hiT[n * 128 + k] = __builtin_bit_cast(unsigned short, h);
    loT[n * 128 + k] = __builtin_bit_cast(unsigned short, l);
}

// ---------------- CSR build helpers ----------------
__global__ void zero_i(int* __restrict__ p, int n) {
    int i = blockIdx.x * 256 + threadIdx.x;
    if (i < n) p[i] = 0;
}

__global__ void count_deg(const int* __restrict__ dst, int* __restrict__ cnt, int E) {
    int e = blockIdx.x * 256 + threadIdx.x;
    if (e < E) atomicAdd(&cnt[dst[e]], 1);
}

// block-level inclusive scan (1024 threads), writes exclusive per-element + block total
__global__ void scanA(const int* __restrict__ cnt, int* __restrict__ rowptr,
                      int* __restrict__ bsum, int N) {
    __shared__ int s[1024];
    int t = threadIdx.x;
    int idx = blockIdx.x * 1024 + t;
    int v = (idx < N) ? cnt[idx] : 0;
    int sum = v;
    s[t] = sum;
    __syncthreads();
    for (int o = 1; o < 1024; o <<= 1) {
        int u = (t >= o) ? s[t - o] : 0;
        __syncthreads();
        sum += u;
        s[t] = sum;
        __syncthreads();
    }
    if (idx < N) rowptr[idx] = sum - v;       // block-local exclusive
    if (t == 1023) bsum[blockIdx.x] = sum;    // block total
}

// single-block exclusive scan of block sums (nb <= 128)
__global__ void scanB(int* __restrict__ bsum, int nb) {
    __shared__ int s[128];
    int t = threadIdx.x;
    int v = (t < nb) ? bsum[t] : 0;
    int sum = v;
    s[t] = sum;
    __syncthreads();
    for (int o = 1; o < 128; o <<= 1) {
        int u = (t >= o) ? s[t - o] : 0;
        __syncthreads();
        sum += u;
        s[t] = sum;
        __syncthreads();
    }
    if (t < nb) bsum[t] = sum - v;            // exclusive
}

// finalize: absolute rowptr, cursor copy, dinv = rsqrt(deg+1)
__global__ void scanC(int* __restrict__ rowptr, const int* __restrict__ bsum,
                      int* __restrict__ cnt_cursor, float* __restrict__ dinv, int N, int E) {
    int i = blockIdx.x * 256 + threadIdx.x;
    if (i < N) {
        int c = cnt_cursor[i];                // raw count (read before overwrite)
        int a = rowptr[i] + bsum[i >> 10];
        rowptr[i] = a;
        cnt_cursor[i] = a;                    // becomes fill cursor
        dinv[i] = rsqrtf((float)(c + 1));     // +1 self-loop; deg >= 1 always
    }
    if (i == 0) rowptr[N] = E;
}

__global__ void fill_csr(const int* __restrict__ src, const int* __restrict__ dst,
                         int* __restrict__ cursor, int* __restrict__ colsrc, int E) {
    int e = blockIdx.x * 256 + threadIdx.x;
    if (e < E) {
        int d = dst[e];
        int p = atomicAdd(&cursor[d], 1);
        colsrc[p] = src[e];
    }
}

// ---------------- GEMM: C[M,128] = A[M,128] @ W[128,128], split-bf16 MFMA ----------------
// mode 0: none; mode 1: +bias then PReLU; mode 2: +bias
__global__ __launch_bounds__(256) void gemm128(
    const float* __restrict__ A, const unsigned short* __restrict__ WhiT,
    const unsigned short* __restrict__ WloT, const float* __restrict__ bias,
    const float* __restrict__ prelu_a, float* __restrict__ C, int M, int mode)
{
    __shared__ unsigned short sHi[128 * 136];   // WT hi, padded stride 136 (bank-friendly)
    __shared__ unsigned short sLo[128 * 136];
    const int tid = threadIdx.x;

    // stage WT hi/lo into LDS: 2048 chunks of 8 ushorts each
    for (int i = tid; i < 2048; i += 256) {
        int row = i >> 4, seg = i & 15;
        *(us8*)(&sHi[row * 136 + seg * 8]) = *(const us8*)(WhiT + row * 128 + seg * 8);
        *(us8*)(&sLo[row * 136 + seg * 8]) = *(const us8*)(WloT + row * 128 + seg * 8);
    }
    __syncthreads();

    const int lane = tid & 63;
    const int wave = tid >> 6;        // 0..3
    const int lc   = lane & 15;       // A frag row / B,C frag col
    const int quad = lane >> 4;       // 0..3
    const int rowBlock = blockIdx.x * 128 + wave * 32;

    f32x4 acc[2][8];
    const f32x4 z4 = {0.f, 0.f, 0.f, 0.f};
#pragma unroll
    for (int rs = 0; rs < 2; ++rs)
#pragma unroll
        for (int t = 0; t < 8; ++t) acc[rs][t] = z4;

#pragma unroll
    for (int ks = 0; ks < 4; ++ks) {
        const int kf = ks * 32 + quad * 8;    // this lane's 8-wide k segment
        bf16x8 ahi[2], alo[2];
#pragma unroll
        for (int rs = 0; rs < 2; ++rs) {
            int r = rowBlock + rs * 16 + lc;
            if (r > M - 1) r = M - 1;         // clamp loads; stores guarded below
            const f32x4* ap = (const f32x4*)(A + (size_t)r * 128 + kf);
            f32x4 a0 = ap[0];
            f32x4 a1 = ap[1];
#pragma unroll
            for (int j = 0; j < 4; ++j) {
                float f = a0[j];
                __bf16 h = (__bf16)f;
                ahi[rs][j] = h;
                alo[rs][j] = (__bf16)(f - (float)h);
            }
#pragma unroll
            for (int j = 0; j < 4; ++j) {
                float f = a1[j];
                __bf16 h = (__bf16)f;
                ahi[rs][4 + j] = h;
                alo[rs][4 + j] = (__bf16)(f - (float)h);
            }
        }
#pragma unroll
        for (int t = 0; t < 8; ++t) {
            bf16x8 bhi = *(const bf16x8*)(&sHi[(t * 16 + lc) * 136 + kf]);
            bf16x8 blo = *(const bf16x8*)(&sLo[(t * 16 + lc) * 136 + kf]);
#pragma unroll
            for (int rs = 0; rs < 2; ++rs) {
                acc[rs][t] = __builtin_amdgcn_mfma_f32_16x16x32_bf16(ahi[rs], bhi, acc[rs][t], 0, 0, 0);
                acc[rs][t] = __builtin_amdgcn_mfma_f32_16x16x32_bf16(ahi[rs], blo, acc[rs][t], 0, 0, 0);
                acc[rs][t] = __builtin_amdgcn_mfma_f32_16x16x32_bf16(alo[rs], bhi, acc[rs][t], 0, 0, 0);
            }
        }
    }

    float av = (mode == 1) ? prelu_a[0] : 0.f;
#pragma unroll
    for (int t = 0; t < 8; ++t) {
        int gcol = t * 16 + lc;
        float bv = (mode != 0) ? bias[gcol] : 0.f;
#pragma unroll
        for (int rs = 0; rs < 2; ++rs) {
#pragma unroll
            for (int i = 0; i < 4; ++i) {
                int r = rowBlock + rs * 16 + quad * 4 + i;   // C/D: row = quad*4+reg
                if (r < M) {
                    float v = acc[rs][t][i] + bv;
                    if (mode == 1) v = (v > 0.f) ? v : av * v;
                    C[(size_t)r * 128 + gcol] = v;
                }
            }
        }
    }
}

// ---------------- GCN aggregation: out[n] = relu(sum_{s in N(n)} h[s]*dinv[s]*dinv[n] + h[n]*dinv[n]^2 + b) ----------------
__global__ void aggregate(const float* __restrict__ h, const float* __restrict__ dinv,
                          const int* __restrict__ rowptr, const int* __restrict__ colsrc,
                          const float* __restrict__ bias, float* __restrict__ out, int N)
{
    int n = blockIdx.x;
    int t = threadIdx.x;                       // 0..127, one feature each
    float dn = dinv[n];
    float acc = h[(size_t)n * 128 + t] * dn * dn;   // self-loop
    int beg = rowptr[n], end = rowptr[n + 1];
    for (int i = beg; i < end; ++i) {
        int s = colsrc[i];
        acc += h[(size_t)s * 128 + t] * (dinv[s] * dn);
    }
    acc += bias[t];
    out[(size_t)n * 128 + t] = fmaxf(acc, 0.f);
}

// ---------------- launch ----------------
extern "C" void kernel_launch(void* const* d_in, const int* in_sizes, int n_in,
                              void* d_out, int out_size, void* d_ws, size_t ws_size,
                              hipStream_t stream)
{
    const float* x   = (const float*)d_in[0];
    const int*   ei  = (const int*)d_in[1];
    const float* W1  = (const float*)d_in[2];
    const float* b1  = (const float*)d_in[3];
    const float* W2  = (const float*)d_in[4];
    const float* b2  = (const float*)d_in[5];
    const float* Wp1 = (const float*)d_in[6];
    const float* bp1 = (const float*)d_in[7];
    const float* pa  = (const float*)d_in[8];
    const float* Wp2 = (const float*)d_in[9];
    const float* bp2 = (const float*)d_in[10];

    const int N = in_sizes[0] / 128;
    const int E = in_sizes[1] / 2;
    const int* src = ei;
    const int* dst = ei + E;

    float* outF = (float*)d_out;
    float* zbuf = outF;                        // output 0: z
    float* pbuf = outF + (size_t)N * 128;      // output 1: p (also used as z1 scratch)

    // workspace carve-up (~57 MB)
    char* w = (char*)d_ws;
    size_t off = 0;
    auto alloc = [&](size_t bytes) {
        void* p = w + off;
        off = (off + bytes + 255) & ~(size_t)255;
        return p;
    };
    float* hbuf   = (float*)alloc((size_t)N * 128 * sizeof(float));
    float* dinv   = (float*)alloc((size_t)N * sizeof(float));
    int*   rowptr = (int*)alloc((size_t)(N + 1) * sizeof(int));
    int*   cntcur = (int*)alloc((size_t)N * sizeof(int));   // counts, then fill cursor
    int*   colsrc = (int*)alloc((size_t)E * sizeof(int));
    int*   bsum   = (int*)alloc(1024);
    unsigned short* wt = (unsigned short*)alloc((size_t)4 * 2 * 128 * 128 * sizeof(unsigned short));
    (void)ws_size; (void)n_in; (void)out_size;

    auto hiP = [&](int m) { return wt + (size_t)m * 2 * 16384; };
    auto loP = [&](int m) { return wt + (size_t)m * 2 * 16384 + 16384; };

    // weight conversion (4 matrices)
    hipLaunchKernelGGL(prep_w, dim3(64), dim3(256), 0, stream, W1,  hiP(0), loP(0));
    hipLaunchKernelGGL(prep_w, dim3(64), dim3(256), 0, stream, W2,  hiP(1), loP(1));
    hipLaunchKernelGGL(prep_w, dim3(64), dim3(256), 0, stream, Wp1, hiP(2), loP(2));
    hipLaunchKernelGGL(prep_w, dim3(64), dim3(256), 0, stream, Wp2, hiP(3), loP(3));

    // CSR by dst + dinv
    const int nb = (N + 1023) >> 10;
    hipLaunchKernelGGL(zero_i,    dim3((N + 255) / 256), dim3(256), 0, stream, cntcur, N);
    hipLaunchKernelGGL(count_deg, dim3((E + 255) / 256), dim3(256), 0, stream, dst, cntcur, E);
    hipLaunchKernelGGL(scanA,     dim3(nb), dim3(1024), 0, stream, cntcur, rowptr, bsum, N);
    hipLaunchKernelGGL(scanB,     dim3(1), dim3(128), 0, stream, bsum, nb);
    hipLaunchKernelGGL(scanC,     dim3((N + 255) / 256), dim3(256), 0, stream, rowptr, bsum, cntcur, dinv, N, E);
    hipLaunchKernelGGL(fill_csr,  dim3((E + 255) / 256), dim3(256), 0, stream, src, dst, cntcur, colsrc, E);

    const int gb = (N + 127) / 128;
    // conv1: h1 = x@W1 ; z1 = relu(agg(h1)+b1) -> pbuf (scratch)
    hipLaunchKernelGGL(gemm128, dim3(gb), dim3(256), 0, stream, x, hiP(0), loP(0),
                       (const float*)nullptr, (const float*)nullptr, hbuf, N, 0);
    hipLaunchKernelGGL(aggregate, dim3(N), dim3(128), 0, stream, hbuf, dinv, rowptr, colsrc, b1, pbuf, N);
    // conv2: h2 = z1@W2 ; z = relu(agg(h2)+b2) -> zbuf (output 0)
    hipLaunchKernelGGL(gemm128, dim3(gb), dim3(256), 0, stream, pbuf, hiP(1), loP(1),
                       (const float*)nullptr, (const float*)nullptr, hbuf, N, 0);
    hipLaunchKernelGGL(aggregate, dim3(N), dim3(128), 0, stream, hbuf, dinv, rowptr, colsrc, b2, zbuf, N);
    // projection: h = prelu(z@Wp1+bp1) -> hbuf ; p = h@Wp2+bp2 -> pbuf (output 1)
    hipLaunchKernelGGL(gemm128, dim3(gb), dim3(256), 0, stream, zbuf, hiP(2), loP(2),
                       bp1, pa, hbuf, N, 1);
    hipLaunchKernelGGL(gemm128, dim3(gb), dim3(256), 0, stream, hbuf, hiP(3), loP(3),
                       bp2, (const float*)nullptr, pbuf, N, 2);
}

// Round 2
// 568.949 us; speedup vs baseline: 1.1533x; 1.1533x over previous
//
#include <hip/hip_runtime.h>

typedef __bf16 bf16x8 __attribute__((ext_vector_type(8)));
typedef float  f32x4  __attribute__((ext_vector_type(4)));
typedef unsigned short us8 __attribute__((ext_vector_type(8)));
typedef unsigned short us4 __attribute__((ext_vector_type(4)));

__device__ __forceinline__ float bf2f(unsigned short u) {
    return __builtin_bit_cast(float, (unsigned int)u << 16);
}
__device__ __forceinline__ unsigned short f2bf(float f) {
    return __builtin_bit_cast(unsigned short, (__bf16)f);
}

// ---------------- weight prep: f32 W[k][n] -> transposed bf16 hi/lo WT[n][k] ----------------
__global__ void prep_w(const float* __restrict__ W, unsigned short* __restrict__ hiT,
                       unsigned short* __restrict__ loT) {
    int i = blockIdx.x * 256 + threadIdx.x;   // 0..16383
    int k = i >> 7;
    int n = i & 127;
    float f = W[i];
    __bf16 h = (__bf16)f;
    __bf16 l = (__bf16)(f - (float)h);
    hiT[n * 128 + k] = __builtin_bit_cast(unsigned short, h);
    loT[n * 128 + k] = __builtin_bit_cast(unsigned short, l);
}

// ---------------- f32 -> bf16 plane (x conversion) ----------------
__global__ void to_bf16(const float* __restrict__ in, unsigned short* __restrict__ out, int n4) {
    int i = blockIdx.x * 256 + threadIdx.x;
    if (i < n4) {
        f32x4 v = ((const f32x4*)in)[i];
        us4 o;
        o[0] = f2bf(v[0]); o[1] = f2bf(v[1]); o[2] = f2bf(v[2]); o[3] = f2bf(v[3]);
        ((us4*)out)[i] = o;
    }
}

// ---------------- CSR build helpers ----------------
__global__ void zero_i(int* __restrict__ p, int n) {
    int i = blockIdx.x * 256 + threadIdx.x;
    if (i < n) p[i] = 0;
}

__global__ void count_deg(const int* __restrict__ dst, int* __restrict__ cnt, int E) {
    int e = blockIdx.x * 256 + threadIdx.x;
    if (e < E) atomicAdd(&cnt[dst[e]], 1);
}

__global__ void scanA(const int* __restrict__ cnt, int* __restrict__ rowptr,
                      int* __restrict__ bsum, int N) {
    __shared__ int s[1024];
    int t = threadIdx.x;
    int idx = blockIdx.x * 1024 + t;
    int v = (idx < N) ? cnt[idx] : 0;
    int sum = v;
    s[t] = sum;
    __syncthreads();
    for (int o = 1; o < 1024; o <<= 1) {
        int u = (t >= o) ? s[t - o] : 0;
        __syncthreads();
        sum += u;
        s[t] = sum;
        __syncthreads();
    }
    if (idx < N) rowptr[idx] = sum - v;
    if (t == 1023) bsum[blockIdx.x] = sum;
}

__global__ void scanB(int* __restrict__ bsum, int nb) {
    __shared__ int s[128];
    int t = threadIdx.x;
    int v = (t < nb) ? bsum[t] : 0;
    int sum = v;
    s[t] = sum;
    __syncthreads();
    for (int o = 1; o < 128; o <<= 1) {
        int u = (t >= o) ? s[t - o] : 0;
        __syncthreads();
        sum += u;
        s[t] = sum;
        __syncthreads();
    }
    if (t < nb) bsum[t] = sum - v;
}

__global__ void scanC(int* __restrict__ rowptr, const int* __restrict__ bsum,
                      int* __restrict__ cnt_cursor, float* __restrict__ dinv, int N, int E) {
    int i = blockIdx.x * 256 + threadIdx.x;
    if (i < N) {
        int c = cnt_cursor[i];
        int a = rowptr[i] + bsum[i >> 10];
        rowptr[i] = a;
        cnt_cursor[i] = a;
        dinv[i] = rsqrtf((float)(c + 1));
    }
    if (i == 0) rowptr[N] = E;
}

__global__ void fill_csr(const int* __restrict__ src, const int* __restrict__ dst,
                         int* __restrict__ cursor, int* __restrict__ colsrc, int E) {
    int e = blockIdx.x * 256 + threadIdx.x;
    if (e < E) {
        int d = dst[e];
        int p = atomicAdd(&cursor[d], 1);
        colsrc[p] = src[e];
    }
}

// ---------------- GEMM: C[M,128] = A[M,128](bf16) @ W[128,128](split hi/lo) ----------------
// mode 0: no bias, write Cb (bf16); mode 1: +bias, PReLU, write Cb; mode 2: +bias, write Cf (f32)
__global__ __launch_bounds__(256) void gemm128s(
    const unsigned short* __restrict__ Ahi, const unsigned short* __restrict__ WhiT,
    const unsigned short* __restrict__ WloT, const float* __restrict__ bias,
    const float* __restrict__ prelu_a, float* __restrict__ Cf,
    unsigned short* __restrict__ Cb, int M, int mode)
{
    __shared__ unsigned short sHi[128 * 136];   // padded stride 136 (no bank conflicts measured)
    __shared__ unsigned short sLo[128 * 136];
    const int tid = threadIdx.x;

    for (int i = tid; i < 2048; i += 256) {
        int row = i >> 4, seg = i & 15;
        *(us8*)(&sHi[row * 136 + seg * 8]) = *(const us8*)(WhiT + row * 128 + seg * 8);
        *(us8*)(&sLo[row * 136 + seg * 8]) = *(const us8*)(WloT + row * 128 + seg * 8);
    }
    __syncthreads();

    const int lane = tid & 63;
    const int wave = tid >> 6;
    const int lc   = lane & 15;       // A frag row / B,C frag col
    const int quad = lane >> 4;
    const int rowBlock = blockIdx.x * 128 + wave * 32;

    f32x4 acc[2][8];
    const f32x4 z4 = {0.f, 0.f, 0.f, 0.f};
#pragma unroll
    for (int rs = 0; rs < 2; ++rs)
#pragma unroll
        for (int t = 0; t < 8; ++t) acc[rs][t] = z4;

#pragma unroll
    for (int ks = 0; ks < 4; ++ks) {
        const int kf = ks * 32 + quad * 8;
        bf16x8 a[2];
#pragma unroll
        for (int rs = 0; rs < 2; ++rs) {
            int r = rowBlock + rs * 16 + lc;
            if (r > M - 1) r = M - 1;
            a[rs] = __builtin_bit_cast(bf16x8, *(const us8*)(Ahi + (size_t)r * 128 + kf));
        }
#pragma unroll
        for (int t = 0; t < 8; ++t) {
            bf16x8 bhi = __builtin_bit_cast(bf16x8, *(const us8*)(&sHi[(t * 16 + lc) * 136 + kf]));
            bf16x8 blo = __builtin_bit_cast(bf16x8, *(const us8*)(&sLo[(t * 16 + lc) * 136 + kf]));
#pragma unroll
            for (int rs = 0; rs < 2; ++rs) {
                acc[rs][t] = __builtin_amdgcn_mfma_f32_16x16x32_bf16(a[rs], bhi, acc[rs][t], 0, 0, 0);
                acc[rs][t] = __builtin_amdgcn_mfma_f32_16x16x32_bf16(a[rs], blo, acc[rs][t], 0, 0, 0);
            }
        }
    }

    float av = (mode == 1) ? prelu_a[0] : 0.f;
#pragma unroll
    for (int t = 0; t < 8; ++t) {
        int gcol = t * 16 + lc;
        float bv = (mode != 0) ? bias[gcol] : 0.f;
#pragma unroll
        for (int rs = 0; rs < 2; ++rs) {
#pragma unroll
            for (int i = 0; i < 4; ++i) {
                int r = rowBlock + rs * 16 + quad * 4 + i;
                if (r < M) {
                    float v = acc[rs][t][i] + bv;
                    if (mode == 1) v = (v > 0.f) ? v : av * v;
                    if (mode == 2) Cf[(size_t)r * 128 + gcol] = v;
                    else           Cb[(size_t)r * 128 + gcol] = f2bf(v);
                }
            }
        }
    }
}

// ---------------- GCN aggregation from bf16 h-plane ----------------
// out[n] = relu( sum_{s in N(n)} h[s]*dinv[s]*dinv[n] + h[n]*dinv[n]^2 + b )
// 4 groups of 32 lanes; group g handles neighbors beg+g, beg+g+4, ... (x2 unrolled);
// lane covers 4 features (ushort4). Cross-group reduce via LDS.
__global__ __launch_bounds__(128) void aggregate(
    const unsigned short* __restrict__ Hhi, const float* __restrict__ dinv,
    const int* __restrict__ rowptr, const int* __restrict__ colsrc,
    const float* __restrict__ bias, float* __restrict__ outF,
    unsigned short* __restrict__ outHi, int N)
{
    const int n = blockIdx.x;
    const int tid = threadIdx.x;     // 0..127
    const int g = tid >> 5;          // group 0..3
    const int l = tid & 31;          // lane in group
    const float dn = dinv[n];
    const int beg = rowptr[n], end = rowptr[n + 1];

    f32x4 a0 = {0.f, 0.f, 0.f, 0.f};
    f32x4 a1 = a0;

    int i = beg + g;
    for (; i + 4 < end; i += 8) {
        int s0 = colsrc[i];
        int s1 = colsrc[i + 4];
        float w0 = dinv[s0] * dn;
        float w1 = dinv[s1] * dn;
        us4 h0 = *(const us4*)(Hhi + (size_t)s0 * 128 + l * 4);
        us4 h1 = *(const us4*)(Hhi + (size_t)s1 * 128 + l * 4);
#pragma unroll
        for (int j = 0; j < 4; ++j) a0[j] += w0 * bf2f(h0[j]);
#pragma unroll
        for (int j = 0; j < 4; ++j) a1[j] += w1 * bf2f(h1[j]);
    }
    if (i < end) {
        int s0 = colsrc[i];
        float w0 = dinv[s0] * dn;
        us4 h0 = *(const us4*)(Hhi + (size_t)s0 * 128 + l * 4);
#pragma unroll
        for (int j = 0; j < 4; ++j) a0[j] += w0 * bf2f(h0[j]);
    }

    __shared__ f32x4 red[128];
    red[tid] = a0 + a1;
    __syncthreads();

    if (tid < 32) {
        f32x4 sum = red[tid] + red[32 + tid] + red[64 + tid] + red[96 + tid];
        us4 sh = *(const us4*)(Hhi + (size_t)n * 128 + tid * 4);
        f32x4 b4 = *(const f32x4*)(bias + tid * 4);
        float ws = dn * dn;
        f32x4 v;
        us4 ob;
#pragma unroll
        for (int j = 0; j < 4; ++j) {
            v[j] = fmaxf(sum[j] + ws * bf2f(sh[j]) + b4[j], 0.f);
            ob[j] = f2bf(v[j]);
        }
        if (outF) *(f32x4*)(outF + (size_t)n * 128 + tid * 4) = v;
        *(us4*)(outHi + (size_t)n * 128 + tid * 4) = ob;
    }
}

// ---------------- launch ----------------
extern "C" void kernel_launch(void* const* d_in, const int* in_sizes, int n_in,
                              void* d_out, int out_size, void* d_ws, size_t ws_size,
                              hipStream_t stream)
{
    const float* x   = (const float*)d_in[0];
    const int*   ei  = (const int*)d_in[1];
    const float* W1  = (const float*)d_in[2];
    const float* b1  = (const float*)d_in[3];
    const float* W2  = (const float*)d_in[4];
    const float* b2  = (const float*)d_in[5];
    const float* Wp1 = (const float*)d_in[6];
    const float* bp1 = (const float*)d_in[7];
    const float* pa  = (const float*)d_in[8];
    const float* Wp2 = (const float*)d_in[9];
    const float* bp2 = (const float*)d_in[10];

    const int N = in_sizes[0] / 128;
    const int E = in_sizes[1] / 2;
    const int* src = ei;
    const int* dst = ei + E;

    float* outF = (float*)d_out;
    float* zbuf = outF;                        // output 0: z
    float* pbuf = outF + (size_t)N * 128;      // output 1: p

    char* w = (char*)d_ws;
    size_t off = 0;
    auto alloc = [&](size_t bytes) {
        void* p = w + off;
        off = (off + bytes + 255) & ~(size_t)255;
        return p;
    };
    unsigned short* S1 = (unsigned short*)alloc((size_t)N * 128 * sizeof(unsigned short));
    unsigned short* S2 = (unsigned short*)alloc((size_t)N * 128 * sizeof(unsigned short));
    float* dinv   = (float*)alloc((size_t)N * sizeof(float));
    int*   rowptr = (int*)alloc((size_t)(N + 1) * sizeof(int));
    int*   cntcur = (int*)alloc((size_t)N * sizeof(int));
    int*   colsrc = (int*)alloc((size_t)E * sizeof(int));
    int*   bsum   = (int*)alloc(1024);
    unsigned short* wt = (unsigned short*)alloc((size_t)4 * 2 * 128 * 128 * sizeof(unsigned short));
    (void)ws_size; (void)n_in; (void)out_size;

    auto hiP = [&](int m) { return wt + (size_t)m * 2 * 16384; };
    auto loP = [&](int m) { return wt + (size_t)m * 2 * 16384 + 16384; };

    // weight conversion
    hipLaunchKernelGGL(prep_w, dim3(64), dim3(256), 0, stream, W1,  hiP(0), loP(0));
    hipLaunchKernelGGL(prep_w, dim3(64), dim3(256), 0, stream, W2,  hiP(1), loP(1));
    hipLaunchKernelGGL(prep_w, dim3(64), dim3(256), 0, stream, Wp1, hiP(2), loP(2));
    hipLaunchKernelGGL(prep_w, dim3(64), dim3(256), 0, stream, Wp2, hiP(3), loP(3));

    // x -> bf16 plane S1
    const int n4 = N * 128 / 4;
    hipLaunchKernelGGL(to_bf16, dim3((n4 + 255) / 256), dim3(256), 0, stream, x, S1, n4);

    // CSR by dst + dinv
    const int nb = (N + 1023) >> 10;
    hipLaunchKernelGGL(zero_i,    dim3((N + 255) / 256), dim3(256), 0, stream, cntcur, N);
    hipLaunchKernelGGL(count_deg, dim3((E + 255) / 256), dim3(256), 0, stream, dst, cntcur, E);
    hipLaunchKernelGGL(scanA,     dim3(nb), dim3(1024), 0, stream, cntcur, rowptr, bsum, N);
    hipLaunchKernelGGL(scanB,     dim3(1), dim3(128), 0, stream, bsum, nb);
    hipLaunchKernelGGL(scanC,     dim3((N + 255) / 256), dim3(256), 0, stream, rowptr, bsum, cntcur, dinv, N, E);
    hipLaunchKernelGGL(fill_csr,  dim3((E + 255) / 256), dim3(256), 0, stream, src, dst, cntcur, colsrc, E);

    const int gb = (N + 127) / 128;
    // conv1: h1 = x@W1 (bf16) -> S2 ; z1 = relu(agg(h1)+b1) -> S1
    hipLaunchKernelGGL(gemm128s, dim3(gb), dim3(256), 0, stream, S1, hiP(0), loP(0),
                       (const float*)nullptr, (const float*)nullptr, (float*)nullptr, S2, N, 0);
    hipLaunchKernelGGL(aggregate, dim3(N), dim3(128), 0, stream, S2, dinv, rowptr, colsrc,
                       b1, (float*)nullptr, S1, N);
    // conv2: h2 = z1@W2 -> S2 ; z = relu(agg(h2)+b2) -> zbuf(f32) + S1(bf16)
    hipLaunchKernelGGL(gemm128s, dim3(gb), dim3(256), 0, stream, S1, hiP(1), loP(1),
                       (const float*)nullptr, (const float*)nullptr, (float*)nullptr, S2, N, 0);
    hipLaunchKernelGGL(aggregate, dim3(N), dim3(128), 0, stream, S2, dinv, rowptr, colsrc,
                       b2, zbuf, S1, N);
    // projection: h = prelu(z@Wp1+bp1) -> S2 ; p = h@Wp2+bp2 -> pbuf(f32)
    hipLaunchKernelGGL(gemm128s, dim3(gb), dim3(256), 0, stream, S1, hiP(2), loP(2),
                       bp1, pa, (float*)nullptr, S2, N, 1);
    hipLaunchKernelGGL(gemm128s, dim3(gb), dim3(256), 0, stream, S2, hiP(3), loP(3),
                       bp2, (const float*)nullptr, pbuf, (unsigned short*)nullptr, N, 2);
}

// Round 3
// 492.958 us; speedup vs baseline: 1.3311x; 1.1542x over previous
//
#include <hip/hip_runtime.h>

typedef __bf16 bf16x8 __attribute__((ext_vector_type(8)));
typedef float  f32x4  __attribute__((ext_vector_type(4)));
typedef unsigned short us8 __attribute__((ext_vector_type(8)));
typedef unsigned short us4 __attribute__((ext_vector_type(4)));

__device__ __forceinline__ float bf2f(unsigned short u) {
    return __builtin_bit_cast(float, (unsigned int)u << 16);
}
__device__ __forceinline__ unsigned short f2bf(float f) {
    return __builtin_bit_cast(unsigned short, (__bf16)f);
}

// ---------------- fused weight prep: 4x f32 W[k][n] -> transposed bf16 hi/lo planes ----------------
// wt layout per matrix m: [m*32768 .. ]: hiT[128*128], loT[128*128]
__global__ void prep_w4(const float* __restrict__ W0, const float* __restrict__ W1,
                        const float* __restrict__ W2, const float* __restrict__ W3,
                        unsigned short* __restrict__ wt) {
    int i = blockIdx.x * 256 + threadIdx.x;    // 0..65535
    int m = i >> 14, r = i & 16383;
    const float* W = (m == 0) ? W0 : (m == 1) ? W1 : (m == 2) ? W2 : W3;
    float f = W[r];
    int k = r >> 7, n = r & 127;
    __bf16 h = (__bf16)f;
    __bf16 l = (__bf16)(f - (float)h);
    unsigned short* base = wt + m * 32768;
    base[n * 128 + k]         = __builtin_bit_cast(unsigned short, h);
    base[16384 + n * 128 + k] = __builtin_bit_cast(unsigned short, l);
}

// ---------------- f32 -> bf16 plane (x conversion) ----------------
__global__ void to_bf16(const float* __restrict__ in, unsigned short* __restrict__ out, int n4) {
    int i = blockIdx.x * 256 + threadIdx.x;
    if (i < n4) {
        f32x4 v = ((const f32x4*)in)[i];
        us4 o;
        o[0] = f2bf(v[0]); o[1] = f2bf(v[1]); o[2] = f2bf(v[2]); o[3] = f2bf(v[3]);
        ((us4*)out)[i] = o;
    }
}

// ---------------- CSR build ----------------
__global__ void count_deg(const int* __restrict__ dst, int* __restrict__ cnt, int E) {
    int e = blockIdx.x * 256 + threadIdx.x;
    if (e < E) atomicAdd(&cnt[dst[e]], 1);
}

__global__ void scanA(const int* __restrict__ cnt, int* __restrict__ rowptr,
                      int* __restrict__ bsum, int N) {
    __shared__ int s[1024];
    int t = threadIdx.x;
    int idx = blockIdx.x * 1024 + t;
    int v = (idx < N) ? cnt[idx] : 0;
    int sum = v;
    s[t] = sum;
    __syncthreads();
    for (int o = 1; o < 1024; o <<= 1) {
        int u = (t >= o) ? s[t - o] : 0;
        __syncthreads();
        sum += u;
        s[t] = sum;
        __syncthreads();
    }
    if (idx < N) rowptr[idx] = sum - v;
    if (t == 1023) bsum[blockIdx.x] = sum;
}

__global__ void scanB(int* __restrict__ bsum, int nb) {
    __shared__ int s[128];
    int t = threadIdx.x;
    int v = (t < nb) ? bsum[t] : 0;
    int sum = v;
    s[t] = sum;
    __syncthreads();
    for (int o = 1; o < 128; o <<= 1) {
        int u = (t >= o) ? s[t - o] : 0;
        __syncthreads();
        sum += u;
        s[t] = sum;
        __syncthreads();
    }
    if (t < nb) bsum[t] = sum - v;
}

// finalize: absolute rowptr, fill cursor, dinv, selfw = dinv^2
__global__ void scanC(int* __restrict__ rowptr, const int* __restrict__ bsum,
                      int* __restrict__ cnt_cursor, float* __restrict__ dinv,
                      float* __restrict__ selfw, int N, int E) {
    int i = blockIdx.x * 256 + threadIdx.x;
    if (i < N) {
        int c = cnt_cursor[i];
        int a = rowptr[i] + bsum[i >> 10];
        rowptr[i] = a;
        cnt_cursor[i] = a;
        float dv = rsqrtf((float)(c + 1));
        dinv[i] = dv;
        selfw[i] = dv * dv;
    }
    if (i == 0) rowptr[N] = E;
}

// fill edge records: epack[p] = {src, dinv[src]*dinv[dst]}
__global__ void fill_csr(const int* __restrict__ src, const int* __restrict__ dst,
                         int* __restrict__ cursor, const float* __restrict__ dinv,
                         int2* __restrict__ epack, int E) {
    int e = blockIdx.x * 256 + threadIdx.x;
    if (e < E) {
        int s = src[e];
        int d = dst[e];
        float w = dinv[s] * dinv[d];
        int p = atomicAdd(&cursor[d], 1);
        int2 rec;
        rec.x = s;
        rec.y = __builtin_bit_cast(int, w);
        epack[p] = rec;
    }
}

// ---------------- GEMM: C[M,128] = A[M,128](bf16) @ W[128,128](split hi/lo) ----------------
// mode 0: no bias, write Cb (bf16); mode 1: +bias, PReLU, write Cb; mode 2: +bias, write Cf (f32)
__global__ __launch_bounds__(256) void gemm128s(
    const unsigned short* __restrict__ Ahi, const unsigned short* __restrict__ WhiT,
    const unsigned short* __restrict__ WloT, const float* __restrict__ bias,
    const float* __restrict__ prelu_a, float* __restrict__ Cf,
    unsigned short* __restrict__ Cb, int M, int mode)
{
    __shared__ unsigned short sHi[128 * 136];
    __shared__ unsigned short sLo[128 * 136];
    const int tid = threadIdx.x;

    for (int i = tid; i < 2048; i += 256) {
        int row = i >> 4, seg = i & 15;
        *(us8*)(&sHi[row * 136 + seg * 8]) = *(const us8*)(WhiT + row * 128 + seg * 8);
        *(us8*)(&sLo[row * 136 + seg * 8]) = *(const us8*)(WloT + row * 128 + seg * 8);
    }
    __syncthreads();

    const int lane = tid & 63;
    const int wave = tid >> 6;
    const int lc   = lane & 15;
    const int quad = lane >> 4;
    const int rowBlock = blockIdx.x * 128 + wave * 32;

    f32x4 acc[2][8];
    const f32x4 z4 = {0.f, 0.f, 0.f, 0.f};
#pragma unroll
    for (int rs = 0; rs < 2; ++rs)
#pragma unroll
        for (int t = 0; t < 8; ++t) acc[rs][t] = z4;

#pragma unroll
    for (int ks = 0; ks < 4; ++ks) {
        const int kf = ks * 32 + quad * 8;
        bf16x8 a[2];
#pragma unroll
        for (int rs = 0; rs < 2; ++rs) {
            int r = rowBlock + rs * 16 + lc;
            if (r > M - 1) r = M - 1;
            a[rs] = __builtin_bit_cast(bf16x8, *(const us8*)(Ahi + (size_t)r * 128 + kf));
        }
#pragma unroll
        for (int t = 0; t < 8; ++t) {
            bf16x8 bhi = __builtin_bit_cast(bf16x8, *(const us8*)(&sHi[(t * 16 + lc) * 136 + kf]));
            bf16x8 blo = __builtin_bit_cast(bf16x8, *(const us8*)(&sLo[(t * 16 + lc) * 136 + kf]));
#pragma unroll
            for (int rs = 0; rs < 2; ++rs) {
                acc[rs][t] = __builtin_amdgcn_mfma_f32_16x16x32_bf16(a[rs], bhi, acc[rs][t], 0, 0, 0);
                acc[rs][t] = __builtin_amdgcn_mfma_f32_16x16x32_bf16(a[rs], blo, acc[rs][t], 0, 0, 0);
            }
        }
    }

    float av = (mode == 1) ? prelu_a[0] : 0.f;
#pragma unroll
    for (int t = 0; t < 8; ++t) {
        int gcol = t * 16 + lc;
        float bv = (mode != 0) ? bias[gcol] : 0.f;
#pragma unroll
        for (int rs = 0; rs < 2; ++rs) {
#pragma unroll
            for (int i = 0; i < 4; ++i) {
                int r = rowBlock + rs * 16 + quad * 4 + i;
                if (r < M) {
                    float v = acc[rs][t][i] + bv;
                    if (mode == 1) v = (v > 0.f) ? v : av * v;
                    if (mode == 2) Cf[(size_t)r * 128 + gcol] = v;
                    else           Cb[(size_t)r * 128 + gcol] = f2bf(v);
                }
            }
        }
    }
}

// ---------------- GCN aggregation v3: one 32-lane group per node ----------------
// out[n] = relu( sum_e w_e * h[src_e] + selfw[n]*h[n] + b ), edge records pre-packed.
// 256 threads = 8 groups; no LDS, no syncthreads; 4-deep unrolled gathers.
__global__ __launch_bounds__(256) void aggregate(
    const unsigned short* __restrict__ Hhi, const float* __restrict__ selfw,
    const int* __restrict__ rowptr, const int2* __restrict__ epack,
    const float* __restrict__ bias, float* __restrict__ outF,
    unsigned short* __restrict__ outHi, int N)
{
    const int tid = threadIdx.x;
    const int g = tid >> 5;
    const int l = tid & 31;
    const int n = blockIdx.x * 8 + g;
    if (n >= N) return;

    const int beg = rowptr[n], end = rowptr[n + 1];
    const size_t fo = (size_t)l * 4;           // this lane's 4-feature slot

    f32x4 a0 = {0.f, 0.f, 0.f, 0.f};
    f32x4 a1 = a0, a2 = a0, a3 = a0;

    int i = beg;
    for (; i + 3 < end; i += 4) {
        int2 e0 = epack[i];
        int2 e1 = epack[i + 1];
        int2 e2 = epack[i + 2];
        int2 e3 = epack[i + 3];
        us4 h0 = *(const us4*)(Hhi + (size_t)e0.x * 128 + fo);
        us4 h1 = *(const us4*)(Hhi + (size_t)e1.x * 128 + fo);
        us4 h2 = *(const us4*)(Hhi + (size_t)e2.x * 128 + fo);
        us4 h3 = *(const us4*)(Hhi + (size_t)e3.x * 128 + fo);
        float w0 = __builtin_bit_cast(float, e0.y);
        float w1 = __builtin_bit_cast(float, e1.y);
        float w2 = __builtin_bit_cast(float, e2.y);
        float w3 = __builtin_bit_cast(float, e3.y);
#pragma unroll
        for (int j = 0; j < 4; ++j) a0[j] += w0 * bf2f(h0[j]);
#pragma unroll
        for (int j = 0; j < 4; ++j) a1[j] += w1 * bf2f(h1[j]);
#pragma unroll
        for (int j = 0; j < 4; ++j) a2[j] += w2 * bf2f(h2[j]);
#pragma unroll
        for (int j = 0; j < 4; ++j) a3[j] += w3 * bf2f(h3[j]);
    }
    for (; i < end; ++i) {
        int2 e0 = epack[i];
        us4 h0 = *(const us4*)(Hhi + (size_t)e0.x * 128 + fo);
        float w0 = __builtin_bit_cast(float, e0.y);
#pragma unroll
        for (int j = 0; j < 4; ++j) a0[j] += w0 * bf2f(h0[j]);
    }

    // self + bias + relu
    float sw = selfw[n];
    us4 sh = *(const us4*)(Hhi + (size_t)n * 128 + fo);
    f32x4 b4 = *(const f32x4*)(bias + l * 4);
    f32x4 sum = (a0 + a1) + (a2 + a3);
    f32x4 v;
    us4 ob;
#pragma unroll
    for (int j = 0; j < 4; ++j) {
        v[j] = fmaxf(sum[j] + sw * bf2f(sh[j]) + b4[j], 0.f);
        ob[j] = f2bf(v[j]);
    }
    if (outF) *(f32x4*)(outF + (size_t)n * 128 + fo) = v;
    *(us4*)(outHi + (size_t)n * 128 + fo) = ob;
}

// ---------------- launch ----------------
extern "C" void kernel_launch(void* const* d_in, const int* in_sizes, int n_in,
                              void* d_out, int out_size, void* d_ws, size_t ws_size,
                              hipStream_t stream)
{
    const float* x   = (const float*)d_in[0];
    const int*   ei  = (const int*)d_in[1];
    const float* W1  = (const float*)d_in[2];
    const float* b1  = (const float*)d_in[3];
    const float* W2  = (const float*)d_in[4];
    const float* b2  = (const float*)d_in[5];
    const float* Wp1 = (const float*)d_in[6];
    const float* bp1 = (const float*)d_in[7];
    const float* pa  = (const float*)d_in[8];
    const float* Wp2 = (const float*)d_in[9];
    const float* bp2 = (const float*)d_in[10];

    const int N = in_sizes[0] / 128;
    const int E = in_sizes[1] / 2;
    const int* src = ei;
    const int* dst = ei + E;

    float* outF = (float*)d_out;
    float* zbuf = outF;                        // output 0: z
    float* pbuf = outF + (size_t)N * 128;      // output 1: p

    char* w = (char*)d_ws;
    size_t off = 0;
    auto alloc = [&](size_t bytes) {
        void* p = w + off;
        off = (off + bytes + 255) & ~(size_t)255;
        return p;
    };
    unsigned short* S1 = (unsigned short*)alloc((size_t)N * 128 * sizeof(unsigned short));
    unsigned short* S2 = (unsigned short*)alloc((size_t)N * 128 * sizeof(unsigned short));
    float* dinv   = (float*)alloc((size_t)N * sizeof(float));
    float* selfw  = (float*)alloc((size_t)N * sizeof(float));
    int*   rowptr = (int*)alloc((size_t)(N + 1) * sizeof(int));
    int*   cntcur = (int*)alloc((size_t)N * sizeof(int));
    int2*  epack  = (int2*)alloc((size_t)E * sizeof(int2));
    int*   bsum   = (int*)alloc(1024);
    unsigned short* wt = (unsigned short*)alloc((size_t)4 * 2 * 128 * 128 * sizeof(unsigned short));
    (void)ws_size; (void)n_in; (void)out_size;

    auto hiP = [&](int m) { return wt + (size_t)m * 32768; };
    auto loP = [&](int m) { return wt + (size_t)m * 32768 + 16384; };

    // weight conversion (fused) + x -> bf16
    hipLaunchKernelGGL(prep_w4, dim3(256), dim3(256), 0, stream, W1, W2, Wp1, Wp2, wt);
    const int n4 = N * 128 / 4;
    hipLaunchKernelGGL(to_bf16, dim3((n4 + 255) / 256), dim3(256), 0, stream, x, S1, n4);

    // CSR by dst + per-edge weights
    hipMemsetAsync(cntcur, 0, (size_t)N * sizeof(int), stream);
    const int nb = (N + 1023) >> 10;
    hipLaunchKernelGGL(count_deg, dim3((E + 255) / 256), dim3(256), 0, stream, dst, cntcur, E);
    hipLaunchKernelGGL(scanA,     dim3(nb), dim3(1024), 0, stream, cntcur, rowptr, bsum, N);
    hipLaunchKernelGGL(scanB,     dim3(1), dim3(128), 0, stream, bsum, nb);
    hipLaunchKernelGGL(scanC,     dim3((N + 255) / 256), dim3(256), 0, stream, rowptr, bsum, cntcur, dinv, selfw, N, E);
    hipLaunchKernelGGL(fill_csr,  dim3((E + 255) / 256), dim3(256), 0, stream, src, dst, cntcur, dinv, epack, E);

    const int gb = (N + 127) / 128;
    const int ab = (N + 7) / 8;
    // conv1: h1 = x@W1 -> S2 ; z1 = relu(agg(h1)+b1) -> S1
    hipLaunchKernelGGL(gemm128s, dim3(gb), dim3(256), 0, stream, S1, hiP(0), loP(0),
                       (const float*)nullptr, (const float*)nullptr, (float*)nullptr, S2, N, 0);
    hipLaunchKernelGGL(aggregate, dim3(ab), dim3(256), 0, stream, S2, selfw, rowptr, epack,
                       b1, (float*)nullptr, S1, N);
    // conv2: h2 = z1@W2 -> S2 ; z = relu(agg(h2)+b2) -> zbuf(f32) + S1(bf16)
    hipLaunchKernelGGL(gemm128s, dim3(gb), dim3(256), 0, stream, S1, hiP(1), loP(1),
                       (const float*)nullptr, (const float*)nullptr, (float*)nullptr, S2, N, 0);
    hipLaunchKernelGGL(aggregate, dim3(ab), dim3(256), 0, stream, S2, selfw, rowptr, epack,
                       b2, zbuf, S1, N);
    // projection: h = prelu(z@Wp1+bp1) -> S2 ; p = h@Wp2+bp2 -> pbuf(f32)
    hipLaunchKernelGGL(gemm128s, dim3(gb), dim3(256), 0, stream, S1, hiP(2), loP(2),
                       bp1, pa, (float*)nullptr, S2, N, 1);
    hipLaunchKernelGGL(gemm128s, dim3(gb), dim3(256), 0, stream, S2, hiP(3), loP(3),
                       bp2, (const float*)nullptr, pbuf, (unsigned short*)nullptr, N, 2);
}